// Round 1
// baseline (597.652 us; speedup 1.0000x reference)
//
#include <hip/hip_runtime.h>

// GraphConvolution (hyperbolic GCN layer), c = 1.0
// Inputs: x [N,D] f32, W [D,D] f32, edge_vals [E] f32, rows [E] i32, cols [E] i32
// Output: out [N,D] f32
// N=100000, D=64, E=1600000

#define NN 100000
#define DD 64
#define EE 1600000

__device__ __forceinline__ float wave_reduce_sum(float v) {
    #pragma unroll
    for (int m = 32; m > 0; m >>= 1) v += __shfl_xor(v, m, 64);
    return v;
}

__device__ __forceinline__ float artanh_clip(float x) {
    const float CLIP = 1.0f - 1e-7f;
    x = fminf(fmaxf(x, -CLIP), CLIP);
    return atanhf(x);
}

// Stage 1: hidden = logmap0(mobius_matvec(W, x)) ; one wave per node, lane = feature
__global__ __launch_bounds__(256) void linear_logmap_kernel(
    const float* __restrict__ x, const float* __restrict__ W,
    float* __restrict__ hidden) {
    // W staged in LDS, stride 65 (65%32==1 -> only 2-way bank aliasing, free)
    __shared__ float Wl[64 * 65];
    for (int i = threadIdx.x; i < 64 * 64; i += 256) {
        Wl[(i >> 6) * 65 + (i & 63)] = W[i];
    }
    __syncthreads();

    const int wave = threadIdx.x >> 6;
    const int lane = threadIdx.x & 63;
    const int node = blockIdx.x * 4 + wave;
    if (node >= NN) return;

    const float MIN_NORM = 1e-15f;
    float xv = x[node * DD + lane];
    float x_n = fmaxf(sqrtf(wave_reduce_sum(xv * xv)), MIN_NORM);

    // mx[lane] = sum_j x[j] * W[lane][j]
    float acc = 0.0f;
    const float* wrow = &Wl[lane * 65];
    #pragma unroll
    for (int j = 0; j < 64; ++j) {
        float xj = __shfl(xv, j, 64);
        acc = fmaf(xj, wrow[j], acc);
    }

    float mx_n = fmaxf(sqrtf(wave_reduce_sum(acc * acc)), MIN_NORM);
    // res = tanh(mx_n/x_n * artanh(x_n)) * mx / mx_n   (sc = 1)
    float t = (mx_n / x_n) * artanh_clip(x_n);
    float res = (tanhf(t) / mx_n) * acc;   // mx==0 -> acc==0 -> res==0 naturally

    // hidden = artanh(|res|) * res / |res|  (logmap0)
    float p_n = fmaxf(sqrtf(wave_reduce_sum(res * res)), MIN_NORM);
    float h = (artanh_clip(p_n) / p_n) * res;

    hidden[node * DD + lane] = h;
}

// Stage 2: zero accumulator (d_out is re-poisoned before every timed launch)
__global__ __launch_bounds__(256) void zero_kernel(float4* __restrict__ p, int n4) {
    int i = blockIdx.x * 256 + threadIdx.x;
    if (i < n4) p[i] = make_float4(0.f, 0.f, 0.f, 0.f);
}

// Stage 3: support[rows[e]] += edge_vals[e] * hidden[cols[e]] ; one wave per edge
__global__ __launch_bounds__(256) void scatter_kernel(
    const float* __restrict__ hidden, const float* __restrict__ edge_vals,
    const int* __restrict__ rows, const int* __restrict__ cols,
    float* __restrict__ support) {
    long long tid = (long long)blockIdx.x * 256 + threadIdx.x;
    int e    = (int)(tid >> 6);
    int lane = (int)(tid & 63);
    if (e >= EE) return;
    float v = edge_vals[e];   // same addr across wave -> broadcast from cache
    int r = rows[e];
    int c = cols[e];
    atomicAdd(&support[r * DD + lane], v * hidden[c * DD + lane]);
}

// Stage 4: expmap0 -> relu(logmap0) -> expmap0 -> proj ; in-place on out
__global__ __launch_bounds__(256) void epilogue_kernel(float* __restrict__ out) {
    const int wave = threadIdx.x >> 6;
    const int lane = threadIdx.x & 63;
    const int node = blockIdx.x * 4 + wave;
    if (node >= NN) return;

    const float MIN_NORM = 1e-15f;
    float s = out[node * DD + lane];

    // p = tanh(u_n) * support / u_n    (expmap0, sc=1)
    float u_n = fmaxf(sqrtf(wave_reduce_sum(s * s)), MIN_NORM);
    float p = (tanhf(u_n) / u_n) * s;

    // xt = relu(artanh(p_n) * p / p_n) (logmap0 + relu)
    float pn2 = fmaxf(sqrtf(wave_reduce_sum(p * p)), MIN_NORM);
    float xt = fmaxf((artanh_clip(pn2) / pn2) * p, 0.0f);

    // out = tanh(xt_n) * xt / xt_n     (expmap0)
    float xt_n = fmaxf(sqrtf(wave_reduce_sum(xt * xt)), MIN_NORM);
    float o = (tanhf(xt_n) / xt_n) * xt;

    // proj: clip to ball of radius 1 - 1e-5
    float o_n = fmaxf(sqrtf(wave_reduce_sum(o * o)), MIN_NORM);
    const float MAX_N = 1.0f - 1e-5f;
    if (o_n > MAX_N) o = (o / o_n) * MAX_N;

    out[node * DD + lane] = o;
}

extern "C" void kernel_launch(void* const* d_in, const int* in_sizes, int n_in,
                              void* d_out, int out_size, void* d_ws, size_t ws_size,
                              hipStream_t stream) {
    const float* x    = (const float*)d_in[0];
    const float* W    = (const float*)d_in[1];
    const float* ev   = (const float*)d_in[2];
    const int*   rows = (const int*)d_in[3];
    const int*   cols = (const int*)d_in[4];
    float* out    = (float*)d_out;
    float* hidden = (float*)d_ws;   // N*D floats = 25.6 MB

    linear_logmap_kernel<<<NN / 4, 256, 0, stream>>>(x, W, hidden);

    int n4 = NN * DD / 4;
    zero_kernel<<<(n4 + 255) / 256, 256, 0, stream>>>((float4*)out, n4);

    long long sthreads = (long long)EE * 64;
    scatter_kernel<<<(int)(sthreads / 256), 256, 0, stream>>>(hidden, ev, rows, cols, out);

    epilogue_kernel<<<NN / 4, 256, 0, stream>>>(out);
}

// Round 2
// 378.789 us; speedup vs baseline: 1.5778x; 1.5778x over previous
//
#include <hip/hip_runtime.h>
#include <hip/hip_fp16.h>

// Hyperbolic GCN layer, c = 1.0
// x [N,D] f32, W [D,D] f32, edge_vals [E] f32, rows [E] i32, cols [E] i32 -> out [N,D] f32
#define NN 100000
#define DD 64
#define EE 1600000

__device__ __forceinline__ float frcp(float x) { return __builtin_amdgcn_rcpf(x); }

__device__ __forceinline__ float fast_tanh(float x) {           // x >= 0 here
    float t = __expf(2.0f * x);
    return (t - 1.0f) * frcp(t + 1.0f);
}
__device__ __forceinline__ float fast_atanh(float x) {
    const float CLIP = 1.0f - 1e-7f;
    x = fminf(fmaxf(x, -CLIP), CLIP);
    return 0.5f * __logf((1.0f + x) * frcp(1.0f - x));
}
__device__ __forceinline__ float group16_reduce_sum(float v) {
    #pragma unroll
    for (int m = 8; m > 0; m >>= 1) v += __shfl_xor(v, m, 16);
    return v;
}
__device__ __forceinline__ float wave_reduce_sum(float v) {
    #pragma unroll
    for (int m = 32; m > 0; m >>= 1) v += __shfl_xor(v, m, 64);
    return v;
}

// ---- Stage 1: hidden(fp16) = logmap0(mobius_matvec(W,x)) ----
// 4 nodes per wave: 16-lane groups, lane holds 4 contiguous features (float4).
// Per j: 1 shfl + 1 ds_read_b128 (vs 1 shfl + 1 ds_read_b32 per (node,j) before).
__global__ __launch_bounds__(256) void linear_logmap_kernel(
    const float* __restrict__ x, const float* __restrict__ W,
    __half* __restrict__ hidden) {
    // Wt[j*68 + f] = W[f][j]; stride 68 keeps float4 reads 16B-aligned.
    __shared__ float Wt[64 * 68];
    for (int i = threadIdx.x; i < 64 * 64; i += 256) {
        int f = i >> 6, j = i & 63;          // coalesced read of W[f][j]
        Wt[j * 68 + f] = W[i];               // 8-way bank conflict, once per block
    }
    __syncthreads();

    const int lane = threadIdx.x & 63;
    const int l    = lane & 15;              // lane-in-group
    const int g    = lane >> 4;              // group (node) within wave
    const int wave = threadIdx.x >> 6;
    const int node = blockIdx.x * 16 + wave * 4 + g;

    const float MIN_NORM = 1e-15f;
    float4 xv = ((const float4*)x)[node * 16 + l];   // features 4l..4l+3

    float x2 = xv.x*xv.x + xv.y*xv.y + xv.z*xv.z + xv.w*xv.w;
    float x_n = fmaxf(sqrtf(group16_reduce_sum(x2)), MIN_NORM);

    float4 a = make_float4(0.f, 0.f, 0.f, 0.f);
    #pragma unroll
    for (int s = 0; s < 16; ++s) {
        float xj0 = __shfl(xv.x, s, 16);     // x[node][4s+0]
        float xj1 = __shfl(xv.y, s, 16);
        float xj2 = __shfl(xv.z, s, 16);
        float xj3 = __shfl(xv.w, s, 16);
        const float4 w0 = *(const float4*)&Wt[(4*s+0)*68 + (l<<2)];
        const float4 w1 = *(const float4*)&Wt[(4*s+1)*68 + (l<<2)];
        const float4 w2 = *(const float4*)&Wt[(4*s+2)*68 + (l<<2)];
        const float4 w3 = *(const float4*)&Wt[(4*s+3)*68 + (l<<2)];
        a.x = fmaf(xj0, w0.x, a.x); a.y = fmaf(xj0, w0.y, a.y);
        a.z = fmaf(xj0, w0.z, a.z); a.w = fmaf(xj0, w0.w, a.w);
        a.x = fmaf(xj1, w1.x, a.x); a.y = fmaf(xj1, w1.y, a.y);
        a.z = fmaf(xj1, w1.z, a.z); a.w = fmaf(xj1, w1.w, a.w);
        a.x = fmaf(xj2, w2.x, a.x); a.y = fmaf(xj2, w2.y, a.y);
        a.z = fmaf(xj2, w2.z, a.z); a.w = fmaf(xj2, w2.w, a.w);
        a.x = fmaf(xj3, w3.x, a.x); a.y = fmaf(xj3, w3.y, a.y);
        a.z = fmaf(xj3, w3.z, a.z); a.w = fmaf(xj3, w3.w, a.w);
    }

    float m2 = a.x*a.x + a.y*a.y + a.z*a.z + a.w*a.w;
    float mx_n = fmaxf(sqrtf(group16_reduce_sum(m2)), MIN_NORM);

    float t  = mx_n * frcp(x_n) * fast_atanh(x_n);
    float th = fast_tanh(t);                 // = ||res||  (t >= 0)
    float p_n = fmaxf(th, MIN_NORM);
    // h = atanh(p_n)/p_n * res,  res = th/mx_n * a  ->  hscale = atanh(p_n)/mx_n
    float hscale = fast_atanh(p_n) * frcp(mx_n);

    __half2 h01 = __floats2half2_rn(a.x * hscale, a.y * hscale);
    __half2 h23 = __floats2half2_rn(a.z * hscale, a.w * hscale);
    __half2* hp = (__half2*)hidden + node * 32 + l * 2;
    hp[0] = h01;
    hp[1] = h23;
}

// ---- CSR build ----
__global__ __launch_bounds__(1024) void zero_off_kernel(int* __restrict__ off) {
    int i = blockIdx.x * 1024 + threadIdx.x;
    if (i < NN) off[i] = 0;
}

__global__ __launch_bounds__(256) void hist_kernel(const int* __restrict__ rows,
                                                   int* __restrict__ off) {
    int e = blockIdx.x * 256 + threadIdx.x;
    atomicAdd(&off[rows[e]], 1);
}

template<int BS>
__device__ __forceinline__ int block_excl_scan(int v, int* wsum, int* p_total) {
    const int lane = threadIdx.x & 63;
    const int wv   = threadIdx.x >> 6;
    int inc = v;
    #pragma unroll
    for (int m = 1; m < 64; m <<= 1) {
        int t = __shfl_up(inc, m, 64);
        if (lane >= m) inc += t;
    }
    if (lane == 63) wsum[wv] = inc;
    __syncthreads();
    int carry = 0, total = 0;
    #pragma unroll
    for (int w = 0; w < BS / 64; ++w) {
        int s = wsum[w];
        total += s;
        if (w < wv) carry += s;
    }
    *p_total = total;
    return carry + inc - v;
}

__global__ __launch_bounds__(1024) void scan1_kernel(int* __restrict__ off,
                                                     int* __restrict__ bsum) {
    __shared__ int wsum[16];
    int i = blockIdx.x * 1024 + threadIdx.x;
    int v = (i < NN) ? off[i] : 0;
    int total;
    int ex = block_excl_scan<1024>(v, wsum, &total);
    if (i < NN) off[i] = ex;
    if (threadIdx.x == 0) bsum[blockIdx.x] = total;
}

__global__ __launch_bounds__(128) void scan2_kernel(int* __restrict__ bsum, int nb) {
    __shared__ int wsum[2];
    int t = threadIdx.x;
    int v = (t < nb) ? bsum[t] : 0;
    int total;
    int ex = block_excl_scan<128>(v, wsum, &total);
    if (t < nb) bsum[t] = ex;
}

__global__ __launch_bounds__(1024) void scan3_kernel(int* __restrict__ off,
                                                     const int* __restrict__ bsum) {
    int i = blockIdx.x * 1024 + threadIdx.x;
    if (i < NN) off[i] += bsum[blockIdx.x];
}

// After fill, off[r] = END of bucket r (start is off[r-1], or 0 for r=0).
__global__ __launch_bounds__(256) void fill_kernel(const int* __restrict__ rows,
                                                   const int* __restrict__ cols,
                                                   const float* __restrict__ ev,
                                                   int* __restrict__ off,
                                                   int2* __restrict__ col_val) {
    int e = blockIdx.x * 256 + threadIdx.x;
    int r = rows[e];
    int p = atomicAdd(&off[r], 1);
    col_val[p] = make_int2(cols[e], __float_as_int(ev[e]));
}

// ---- Gather + full epilogue: one wave per node, lane = feature ----
__global__ __launch_bounds__(256) void gather_epilogue_kernel(
    const __half* __restrict__ hidden, const int2* __restrict__ col_val,
    const int* __restrict__ off, float* __restrict__ out) {
    const int wave = threadIdx.x >> 6;
    const int lane = threadIdx.x & 63;
    const int node = blockIdx.x * 4 + wave;

    int rhi = off[node];
    int rlo = (node == 0) ? 0 : off[node - 1];

    float acc = 0.0f;
    int i = rlo;
    for (; i + 4 <= rhi; i += 4) {
        int2 p0 = col_val[i+0], p1 = col_val[i+1];
        int2 p2 = col_val[i+2], p3 = col_val[i+3];
        float h0 = __half2float(hidden[p0.x * DD + lane]);
        float h1 = __half2float(hidden[p1.x * DD + lane]);
        float h2 = __half2float(hidden[p2.x * DD + lane]);
        float h3 = __half2float(hidden[p3.x * DD + lane]);
        acc = fmaf(__int_as_float(p0.y), h0, acc);
        acc = fmaf(__int_as_float(p1.y), h1, acc);
        acc = fmaf(__int_as_float(p2.y), h2, acc);
        acc = fmaf(__int_as_float(p3.y), h3, acc);
    }
    for (; i < rhi; ++i) {
        int2 p = col_val[i];
        acc = fmaf(__int_as_float(p.y), __half2float(hidden[p.x * DD + lane]), acc);
    }

    const float MIN_NORM = 1e-15f;
    // expmap0
    float u_n = fmaxf(sqrtf(wave_reduce_sum(acc * acc)), MIN_NORM);
    float tu  = fast_tanh(u_n);                   // = ||p||
    float p   = tu * frcp(u_n) * acc;
    // relu(logmap0)
    float pn2 = fmaxf(tu, MIN_NORM);
    float xt  = fmaxf(fast_atanh(pn2) * frcp(pn2) * p, 0.0f);
    // expmap0
    float xt_n = fmaxf(sqrtf(wave_reduce_sum(xt * xt)), MIN_NORM);
    float txt  = fast_tanh(xt_n);                 // = ||out||
    float o    = txt * frcp(xt_n) * xt;
    // proj
    float o_n = fmaxf(txt, MIN_NORM);
    const float MAX_N = 1.0f - 1e-5f;
    if (o_n > MAX_N) o *= MAX_N * frcp(o_n);

    out[node * DD + lane] = o;
}

extern "C" void kernel_launch(void* const* d_in, const int* in_sizes, int n_in,
                              void* d_out, int out_size, void* d_ws, size_t ws_size,
                              hipStream_t stream) {
    const float* x    = (const float*)d_in[0];
    const float* W    = (const float*)d_in[1];
    const float* ev   = (const float*)d_in[2];
    const int*   rows = (const int*)d_in[3];
    const int*   cols = (const int*)d_in[4];
    float* out = (float*)d_out;

    char* ws = (char*)d_ws;
    __half* hidden  = (__half*)ws;                          // 12,800,000 B
    int*    off     = (int*)(ws + 12800000);                //    400,000 B
    int*    bsum    = (int*)(ws + 13200000);                //        512 B
    int2*   col_val = (int2*)(ws + 13200512);               // 12,800,000 B
                                                            // total ~26.0 MB

    linear_logmap_kernel<<<NN / 16, 256, 0, stream>>>(x, W, hidden);

    zero_off_kernel<<<98, 1024, 0, stream>>>(off);
    hist_kernel<<<EE / 256, 256, 0, stream>>>(rows, off);
    scan1_kernel<<<98, 1024, 0, stream>>>(off, bsum);
    scan2_kernel<<<1, 128, 0, stream>>>(bsum, 98);
    scan3_kernel<<<98, 1024, 0, stream>>>(off, bsum);
    fill_kernel<<<EE / 256, 256, 0, stream>>>(rows, cols, ev, off, col_val);

    gather_epilogue_kernel<<<NN / 4, 256, 0, stream>>>(hidden, col_val, off, out);
}